// Round 3
// baseline (287.960 us; speedup 1.0000x reference)
//
#include <hip/hip_runtime.h>
#include <cmath>

#define IMG_W 512
#define IMG_H 512
#define NIMG 64
#define OWV 502   // valid-conv output extent (SSIM branch)

struct KTaps {
    float kw[11];   // normalized gaussian, win=11, sigma=1.5 (SSIM)
    float ke[13];   // erf-gaussian, 13 taps, NOT normalized (L1)
};

// Zero-cost ordering pin for cross-lane LDS traffic within one wave:
// emits no instruction, but the compiler may not move memory ops across it.
#define WAVE_FENCE() __builtin_amdgcn_wave_barrier()

// ---------------- Kernel A: SSIM -> scalar sum ----------------
// Wave-autonomous, no barriers in the loop. 4-quantity trick: SSIM only
// needs mx, my, mxx+myy, mxy. Stage {x, y, (x+y)^2, (x-y)^2}; then
// mxx+myy = (A+B)/2, mxy = (A-B)/4 where A=conv(s^2), B=conv(d^2).
// Products are computed ONCE per staged column (not per 12-wide window),
// cutting h-pass VALU from 96 to 44 per iter; v-ring 55 -> 44 FMA.
// Depth-2 register prefetch: row rr+3 loaded at iter rr, staged at iter
// rr+2. Needs compile-time pf-set parity -> 22-phase unroll (lcm(11,2)).
__global__ __launch_bounds__(256) void ssim_band_kernel(
        const float* __restrict__ x, const float* __restrict__ y,
        double* __restrict__ ssum, KTaps kt) {
    // [wave][buf][quant][col]; quant: 0=x 1=y 2=(x+y)^2 3=(x-y)^2
    __shared__ __align__(16) float sq[4][2][4][80];

    const int img   = blockIdx.z;
    const int band  = blockIdx.y;     // 0..7
    const int strip = blockIdx.x;     // 0..1
    const int tid   = threadIdx.x;
    const int w     = tid >> 6;
    const int lane  = tid & 63;
    const int r0    = band * 64;
    const int wc0   = strip * 256 + w * 64;   // wave's first output col

    const float* __restrict__ xi = x + (size_t)img * IMG_H * IMG_W;
    const float* __restrict__ yi = y + (size_t)img * IMG_H * IMG_W;

    // staging: lanes 0..37 load x AND y f2 for cols wc0+2l, wc0+2l+1
    // (76 staged cols = 64 outputs + 11 halo + 1 spare). OOB -> zeros.
    const bool stg = (lane < 38);
    const int  gc  = wc0 + 2 * lane;
    const bool gok = stg && (gc < IMG_W);

    auto ld2 = [&](const float* __restrict__ p, int r) -> float2 {
        float2 v = make_float2(0.f, 0.f);
        if (gok && r < IMG_H) v = *(const float2*)(p + (size_t)r * IMG_W + gc);
        return v;
    };

    // write one staged row into buffer `buf` (squares computed here, once)
    auto stage = [&](int buf, float2 vx, float2 vy) {
        if (stg) {
            const float s0 = vx.x + vy.x, d0 = vx.x - vy.x;
            const float s1 = vx.y + vy.y, d1 = vx.y - vy.y;
            *(float2*)&sq[w][buf][0][2 * lane] = vx;
            *(float2*)&sq[w][buf][1][2 * lane] = vy;
            *(float2*)&sq[w][buf][2][2 * lane] = make_float2(s0 * s0, s1 * s1);
            *(float2*)&sq[w][buf][3][2 * lane] = make_float2(d0 * d0, d1 * d1);
        }
    };

    float acc[11][4];
#pragma unroll
    for (int i = 0; i < 11; ++i)
#pragma unroll
        for (int q = 0; q < 4; ++q) acc[i][q] = 0.f;
    float tsum = 0.f;
    const int outc = wc0 + lane;

    // prologue: row r0 -> buf0; depth-2 prefetch r0+1 -> set1, r0+2 -> set0
    stage(0, ld2(xi, r0), ld2(yi, r0));
    float2 pfx[2], pfy[2];
    pfx[1] = ld2(xi, r0 + 1); pfy[1] = ld2(yi, r0 + 1);
    pfx[0] = ld2(xi, r0 + 2); pfy[0] = ld2(yi, r0 + 2);
    WAVE_FENCE();

#pragma unroll 1
    for (int c2 = 0; c2 < 4; ++c2) {
        const int rbase = c2 * 22;
#pragma unroll
        for (int p22 = 0; p22 < 22; ++p22) {
            const int rr  = rbase + p22;    // runtime base + static phase
            const int p11 = p22 % 11;       // static ring phase
            const int b   = p22 & 1;        // static buffer parity
            if (rr <= 73) {
                // h-pass: 11-tap conv of 4 staged arrays, unaligned scalar
                // LDS reads (compiler pairs to ds_read2_b32; 2-way = free),
                // weights stay in SGPRs (wave-uniform kernarg).
                float h[4];
#pragma unroll
                for (int q = 0; q < 4; ++q) {
                    float a0 = 0.f;
#pragma unroll
                    for (int u = 0; u < 11; ++u)
                        a0 += kt.kw[u] * sq[w][b][q][lane + u];
                    h[q] = a0;
                }
                // stage row rr+1 (loaded 2 iters ago) into other buffer
                if (rr < 73) stage(b ^ 1, pfx[(p22 + 1) & 1], pfy[(p22 + 1) & 1]);
                // reload the just-consumed set with row rr+3 (depth-2)
                if (rr < 71) {
                    pfx[(p22 + 1) & 1] = ld2(xi, r0 + rr + 3);
                    pfy[(p22 + 1) & 1] = ld2(yi, r0 + rr + 3);
                }
                // v-pass: 44 FMAs into mod-11 pending slots (static indices)
#pragma unroll
                for (int d = 0; d <= 10; ++d) {
                    const int s = (p11 + 11 - d) % 11;
                    const float wv = kt.kw[d];
                    acc[s][0] += wv * h[0]; acc[s][1] += wv * h[1];
                    acc[s][2] += wv * h[2]; acc[s][3] += wv * h[3];
                }
                {   // slot (p11+1)%11 completed output row ro = rr-10
                    const int sc = (p11 + 1) % 11;
                    const int ro = rr - 10;
                    if (ro >= 0) {
                        const int o = r0 + ro;
                        if (o < OWV && outc < OWV) {
                            const float mx = acc[sc][0], my = acc[sc][1];
                            const float Aq = acc[sc][2], Bq = acc[sc][3];
                            const float mq   = mx * mx + my * my;
                            const float pxy  = mx * my;
                            const float vsum = 0.5f  * (Aq + Bq) - mq;   // vx+vy
                            const float cov  = 0.25f * (Aq - Bq) - pxy;  // cov
                            const float c1 = 1e-4f, c2c = 9e-4f;
                            const float num = (2.f * pxy + c1) * (2.f * cov + c2c);
                            const float den = (mq + c1) * (vsum + c2c);
                            tsum += num * __builtin_amdgcn_rcpf(den);
                        }
                    }
#pragma unroll
                    for (int q = 0; q < 4; ++q) acc[sc][q] = 0.f;  // ALWAYS reset
                }
                WAVE_FENCE();
            }
        }
    }

    // reduce + one atomic per block (single real barrier in the kernel)
#pragma unroll
    for (int off = 32; off > 0; off >>= 1) tsum += __shfl_down(tsum, off, 64);
    __shared__ float wsum[4];
    if (lane == 0) wsum[w] = tsum;
    __syncthreads();
    if (tid == 0) atomicAdd(ssum, (double)(wsum[0] + wsum[1] + wsum[2] + wsum[3]));
}

// ---------------- Kernel B: L1 map + combine ----------------
// Re-tiled for occupancy: 1 output col per lane, 64-col waves, 2 col-strips
// x 16 bands x 64 imgs = 2048 blocks (8/CU); target <=64 VGPR so 8 waves/SIMD
// become resident (launch_bounds(256,8)). Scalar LDS window reads + SGPR
// taps; depth-2 prefetch with 26-phase unroll (lcm(13,2)).
__global__ __launch_bounds__(256, 8) void l1_band_kernel(
        const float* __restrict__ x, const float* __restrict__ y,
        const double* __restrict__ ssum, float* __restrict__ out, KTaps kt) {
    __shared__ __align__(16) float sdw[4][2][80];   // per-wave dbuf, 76 used

    const int img   = blockIdx.y;
    const int bx    = blockIdx.x;    // 0..31
    const int strip = bx & 1;
    const int band  = bx >> 1;       // 0..15
    const int tid   = threadIdx.x;
    const int w     = tid >> 6;
    const int lane  = tid & 63;
    const int o0    = band * 32;
    const int rin0  = o0 - 6;
    const int wc0   = strip * 256 + w * 64;   // wave's first output col

    const float* __restrict__ xi = x + (size_t)img * IMG_H * IMG_W;
    const float* __restrict__ yi = y + (size_t)img * IMG_H * IMG_W;
    float* __restrict__ oi = out + (size_t)img * IMG_H * IMG_W;

    const float base = 100.f * 0.84f * (1.f - (float)(*ssum) * (1.f / 16128256.f));

    // staging: lanes 0..37 cover local cols 0..75 = global wc0-6 .. wc0+69
    // (64 outputs + 6+6 halo). OOB (left edge / right edge) -> zeros = SAME pad.
    const bool stg = (lane < 38);
    const int  gc  = wc0 - 6 + 2 * lane;
    const bool gok = stg && (gc >= 0) && (gc < IMG_W);

    auto ld2 = [&](const float* __restrict__ p, int r) -> float2 {
        float2 v = make_float2(0.f, 0.f);
        if (gok && r >= 0 && r < IMG_H) v = *(const float2*)(p + (size_t)r * IMG_W + gc);
        return v;
    };
    auto stage = [&](int buf, float2 vx, float2 vy) {   // d = y - x
        if (stg) *(float2*)&sdw[w][buf][2 * lane] =
            make_float2(vy.x - vx.x, vy.y - vx.y);
    };

    float acc[13];
#pragma unroll
    for (int i = 0; i < 13; ++i) acc[i] = 0.f;

    // prologue: row rin0 -> buf0; prefetch rin0+1 -> set1, rin0+2 -> set0
    stage(0, ld2(xi, rin0), ld2(yi, rin0));
    float2 pfx[2], pfy[2];
    pfx[1] = ld2(xi, rin0 + 1); pfy[1] = ld2(yi, rin0 + 1);
    pfx[0] = ld2(xi, rin0 + 2); pfy[0] = ld2(yi, rin0 + 2);
    WAVE_FENCE();

#pragma unroll 1
    for (int c2 = 0; c2 < 2; ++c2) {
        const int rbase = c2 * 26;
#pragma unroll
        for (int p26 = 0; p26 < 26; ++p26) {
            const int rr  = rbase + p26;
            const int p13 = p26 % 13;       // static ring phase
            const int b   = p26 & 1;        // static buffer parity
            if (rr <= 43) {
                // h-pass: 13-tap window, floats lane..lane+12 (scalar reads,
                // compiler pairs; taps in SGPRs)
                float a0 = 0.f;
#pragma unroll
                for (int u = 0; u < 13; ++u)
                    a0 += kt.ke[u] * sdw[w][b][lane + u];
                if (rr < 43) stage(b ^ 1, pfx[(p26 + 1) & 1], pfy[(p26 + 1) & 1]);
                if (rr < 41) {
                    pfx[(p26 + 1) & 1] = ld2(xi, rin0 + rr + 3);
                    pfy[(p26 + 1) & 1] = ld2(yi, rin0 + rr + 3);
                }
                // v-pass into mod-13 pending slots (static indices)
#pragma unroll
                for (int d = 0; d <= 12; ++d)
                    acc[(p13 + 13 - d) % 13] += kt.ke[d] * a0;
                {
                    const int sc = (p13 + 1) % 13;
                    const int ro = rr - 12;
                    if (ro >= 0) {
                        const int o = o0 + ro;   // always in [0,511]
                        oi[(size_t)o * IMG_W + wc0 + lane] =
                            fmaf(16.f, fabsf(acc[sc]), base);
                    }
                    acc[sc] = 0.f;   // ALWAYS reset
                }
                WAVE_FENCE();
            }
        }
    }
}

extern "C" void kernel_launch(void* const* d_in, const int* in_sizes, int n_in,
                              void* d_out, int out_size, void* d_ws, size_t ws_size,
                              hipStream_t stream) {
    const float* x = (const float*)d_in[0];
    const float* y = (const float*)d_in[1];
    float* out = (float*)d_out;
    double* ssum = (double*)d_ws;

    KTaps kt;
    {   // normalized gaussian win=11 sigma=1.5 (exp-based)
        double g[11], s = 0.0;
        for (int i = 0; i < 11; ++i) {
            const double d = (double)i - 5.0;
            g[i] = std::exp(-(d * d) / 4.5);
            s += g[i];
        }
        for (int i = 0; i < 11; ++i) kt.kw[i] = (float)(g[i] / s);
    }
    {   // erf-gaussian, tail=6 -> 13 taps, sigma=1.5, NOT normalized
        const double t = 0.70710678 / 1.5;
        for (int i = 0; i < 13; ++i) {
            const double xx = (double)i - 6.0;
            const double v = 0.5 * (std::erf(t * (xx + 0.5)) - std::erf(t * (xx - 0.5)));
            kt.ke[i] = (float)(v < 0.0 ? 0.0 : v);
        }
    }

    hipMemsetAsync(ssum, 0, sizeof(double), stream);

    ssim_band_kernel<<<dim3(2, 8, NIMG), dim3(256), 0, stream>>>(x, y, ssum, kt);
    l1_band_kernel<<<dim3(32, NIMG, 1), dim3(256), 0, stream>>>(x, y, ssum, out, kt);
}

// Round 4
// 269.648 us; speedup vs baseline: 1.0679x; 1.0679x over previous
//
#include <hip/hip_runtime.h>
#include <cmath>

#define IMG_W 512
#define IMG_H 512
#define NIMG 64
#define OWV 502   // valid-conv output extent (SSIM branch)

typedef _Float16 h2 __attribute__((ext_vector_type(2)));
typedef _Float16 h4 __attribute__((ext_vector_type(4)));
typedef float    f2v __attribute__((ext_vector_type(2)));

struct KTaps {
    float kw[11];   // normalized gaussian, win=11, sigma=1.5 (SSIM)
    float ke[13];   // erf-gaussian, 13 taps, NOT normalized (L1)
};

// Zero-cost ordering pin for cross-lane LDS traffic within one wave.
#define WAVE_FENCE() __builtin_amdgcn_wave_barrier()

#if defined(__has_builtin)
#if __has_builtin(__builtin_amdgcn_fdot2)
#define FDOT2(a, b, c) __builtin_amdgcn_fdot2((a), (b), (c), false)
#endif
#endif
#ifndef FDOT2
static __device__ __forceinline__ float fdot2_sw(h2 a, h2 b, float c) {
    return c + (float)a.x * (float)b.x + (float)a.y * (float)b.y;
}
#define FDOT2(a, b, c) fdot2_sw((a), (b), (c))
#endif

static __device__ __forceinline__ h2 lo2(h4 v) { return __builtin_shufflevector(v, v, 0, 1); }
static __device__ __forceinline__ h2 hi2(h4 v) { return __builtin_shufflevector(v, v, 2, 3); }

// ---------------- Kernel A: SSIM -> scalar sum ----------------
// Wave-autonomous (no barriers in loop). 4-quantity trick: stage
// {s=x+y, d=x-y, s^2, d^2} so SSIM needs only 4 convs (S,D,P,Q):
//   2*mx*my   = (S^2-D^2)/2      mx^2+my^2 = (S^2+D^2)/2
//   mxx+myy   = (P+Q)/2          2*mxy     = (P-Q)/2
// f16 LDS staging halves the dominant LDS-window bytes (176->88 B/output);
// h-pass is v_dot2_f32_f16 (f32 accumulate): 16 ds_read_b64 + 32 fdot2
// per iter replaces 22 ds_read2_b32 + 44 FMA. v-ring is packed f32
// (f2v -> v_pk_fma_f32). Depth-2 register prefetch, 22-phase unroll.
__global__ __launch_bounds__(256) void ssim_band_kernel(
        const float* __restrict__ x, const float* __restrict__ y,
        double* __restrict__ ssum, KTaps kt) {
    // per-wave dbuf planes of 40 h2 (=80 cols staged, 76 used)
    __shared__ __align__(16) h2 pS[4][2][40], pD[4][2][40],
                               pP[4][2][40], pQ[4][2][40];

    const int img   = blockIdx.z;
    const int band  = blockIdx.y;     // 0..7
    const int strip = blockIdx.x;     // 0..1
    const int tid   = threadIdx.x;
    const int w     = tid >> 6;
    const int lane  = tid & 63;
    const int r0    = band * 64;
    const int wc0   = strip * 256 + w * 64;   // wave's first output col

    const float* __restrict__ xi = x + (size_t)img * IMG_H * IMG_W;
    const float* __restrict__ yi = y + (size_t)img * IMG_H * IMG_W;

    // staging: lanes 0..37 load x,y f2 for cols wc0+2l, wc0+2l+1. OOB->0.
    const bool stg = (lane < 38);
    const int  gc  = wc0 + 2 * lane;
    const bool gok = stg && (gc < IMG_W);

    auto ld2 = [&](const float* __restrict__ p, int r) -> float2 {
        float2 v = make_float2(0.f, 0.f);
        if (gok && r < IMG_H) v = *(const float2*)(p + (size_t)r * IMG_W + gc);
        return v;
    };

    // stage one row: compute s,d,s^2,d^2 once per col, write f16 pairs
    auto stage = [&](int buf, float2 vx, float2 vy) {
        if (stg) {
            const float s0 = vx.x + vy.x, d0 = vx.x - vy.x;
            const float s1 = vx.y + vy.y, d1 = vx.y - vy.y;
            h2 a; a.x = (_Float16)s0;        a.y = (_Float16)s1;        pS[w][buf][lane] = a;
            h2 b; b.x = (_Float16)d0;        b.y = (_Float16)d1;        pD[w][buf][lane] = b;
            h2 c; c.x = (_Float16)(s0 * s0); c.y = (_Float16)(s1 * s1); pP[w][buf][lane] = c;
            h2 d; d.x = (_Float16)(d0 * d0); d.y = (_Float16)(d1 * d1); pQ[w][buf][lane] = d;
        }
    };

    // 4-parity packed f16 weights: window halfs [4a .. 4a+15], a=lane>>2,
    // tap u of output col `lane` sits at j = u + (lane&3).
    const int off = lane & 3;
    h2 w2[8];
#pragma unroll
    for (int t = 0; t < 8; ++t) { w2[t].x = (_Float16)0.f; w2[t].y = (_Float16)0.f; }
#pragma unroll
    for (int offc = 0; offc < 4; ++offc) {
        if (off == offc) {
#pragma unroll
            for (int u = 0; u < 11; ++u) {
                const int j = u + offc;           // compile-time per offc
                if (j & 1) w2[j >> 1].y = (_Float16)kt.kw[u];
                else       w2[j >> 1].x = (_Float16)kt.kw[u];
            }
        }
    }
    const int hb = 2 * (lane >> 2);   // h2-index window base (even)

    f2v acc01[11], acc23[11];
#pragma unroll
    for (int i = 0; i < 11; ++i) { acc01[i] = (f2v)0.f; acc23[i] = (f2v)0.f; }
    float tsum = 0.f;
    const int outc = wc0 + lane;

    // prologue: row r0 -> buf0; depth-2 prefetch r0+1 -> set1, r0+2 -> set0
    stage(0, ld2(xi, r0), ld2(yi, r0));
    float2 pfx[2], pfy[2];
    pfx[1] = ld2(xi, r0 + 1); pfy[1] = ld2(yi, r0 + 1);
    pfx[0] = ld2(xi, r0 + 2); pfy[0] = ld2(yi, r0 + 2);
    WAVE_FENCE();

#pragma unroll 1
    for (int c2 = 0; c2 < 4; ++c2) {
        const int rbase = c2 * 22;
#pragma unroll
        for (int p22 = 0; p22 < 22; ++p22) {
            const int rr  = rbase + p22;    // runtime base + static phase
            const int p11 = p22 % 11;       // static ring phase
            const int b   = p22 & 1;        // static buffer parity
            if (rr <= 73) {
                // h-pass: 4 planes x 4 ds_read_b64 + 8 fdot2 each
                float hS = 0.f, hD = 0.f, hP = 0.f, hQ = 0.f;
#pragma unroll
                for (int k = 0; k < 4; ++k) {
                    const h4 vS = *(const h4*)&pS[w][b][hb + 2 * k];
                    const h4 vD = *(const h4*)&pD[w][b][hb + 2 * k];
                    const h4 vP = *(const h4*)&pP[w][b][hb + 2 * k];
                    const h4 vQ = *(const h4*)&pQ[w][b][hb + 2 * k];
                    hS = FDOT2(w2[2 * k], lo2(vS), hS); hS = FDOT2(w2[2 * k + 1], hi2(vS), hS);
                    hD = FDOT2(w2[2 * k], lo2(vD), hD); hD = FDOT2(w2[2 * k + 1], hi2(vD), hD);
                    hP = FDOT2(w2[2 * k], lo2(vP), hP); hP = FDOT2(w2[2 * k + 1], hi2(vP), hP);
                    hQ = FDOT2(w2[2 * k], lo2(vQ), hQ); hQ = FDOT2(w2[2 * k + 1], hi2(vQ), hQ);
                }
                // stage row rr+1 (loaded 2 iters ago) into other buffer
                if (rr < 73) stage(b ^ 1, pfx[(p22 + 1) & 1], pfy[(p22 + 1) & 1]);
                // reload the just-consumed set with row rr+3 (depth-2)
                if (rr < 71) {
                    pfx[(p22 + 1) & 1] = ld2(xi, r0 + rr + 3);
                    pfy[(p22 + 1) & 1] = ld2(yi, r0 + rr + 3);
                }
                // v-pass: 22 packed FMAs into mod-11 pending slots
                f2v h01; h01.x = hS; h01.y = hD;
                f2v h23; h23.x = hP; h23.y = hQ;
#pragma unroll
                for (int d = 0; d <= 10; ++d) {
                    const int s = (p11 + 11 - d) % 11;
                    f2v wv; wv.x = kt.kw[d]; wv.y = kt.kw[d];
                    acc01[s] += wv * h01;
                    acc23[s] += wv * h23;
                }
                {   // slot (p11+1)%11 completed output row ro = rr-10
                    const int sc = (p11 + 1) % 11;
                    const int ro = rr - 10;
                    if (ro >= 0) {
                        const int o = r0 + ro;
                        if (o < OWV && outc < OWV) {
                            const float S = acc01[sc].x, D = acc01[sc].y;
                            const float P = acc23[sc].x, Q = acc23[sc].y;
                            const float S2 = S * S, D2 = D * D;
                            const float mq2  = 0.5f * (S2 + D2);      // mx^2+my^2
                            const float px2  = 0.5f * (S2 - D2);      // 2 mx my
                            const float vsum = 0.5f * (P + Q) - mq2;  // vx+vy
                            const float cov2 = 0.5f * (P - Q) - px2;  // 2 cov
                            const float c1 = 1e-4f, c2c = 9e-4f;
                            const float num = (px2 + c1) * (cov2 + c2c);
                            const float den = (mq2 + c1) * (vsum + c2c);
                            tsum += num * __builtin_amdgcn_rcpf(den);
                        }
                    }
                    acc01[sc] = (f2v)0.f; acc23[sc] = (f2v)0.f;   // ALWAYS reset
                }
                WAVE_FENCE();
            }
        }
    }

    // reduce + one atomic per block (single real barrier in the kernel)
#pragma unroll
    for (int offr = 32; offr > 0; offr >>= 1) tsum += __shfl_down(tsum, offr, 64);
    __shared__ float wsum[4];
    if (lane == 0) wsum[w] = tsum;
    __syncthreads();
    if (tid == 0) atomicAdd(ssum, (double)(wsum[0] + wsum[1] + wsum[2] + wsum[3]));
}

// ---------------- Kernel B: L1 map + combine ----------------
// R2 geometry (full-width 4-wave blocks, 2 cols/lane, float2 stores, NO
// forced launch bounds) + wave-autonomy + depth-2 prefetch + f16 window
// (4 ds_read_b64 + 16 fdot2 serve BOTH columns) + packed f32 v-ring.
__global__ __launch_bounds__(256) void l1_band_kernel(
        const float* __restrict__ x, const float* __restrict__ y,
        const double* __restrict__ ssum, float* __restrict__ out, KTaps kt) {
    __shared__ __align__(16) h2 sdw[4][2][72];   // per-wave dbuf, 70 h2 used

    const int img  = blockIdx.y;
    const int band = blockIdx.x;   // 0..15
    const int tid  = threadIdx.x;
    const int w    = tid >> 6;
    const int lane = tid & 63;
    const int o0   = band * 32;
    const int rin0 = o0 - 6;
    const int wc0  = w * 128;      // wave's first output col

    const float* __restrict__ xi = x + (size_t)img * IMG_H * IMG_W;
    const float* __restrict__ yi = y + (size_t)img * IMG_H * IMG_W;
    float* __restrict__ oi = out + (size_t)img * IMG_H * IMG_W;

    const float base = 100.f * 0.84f * (1.f - (float)(*ssum) * (1.f / 16128256.f));

    // staging: lane l -> local h2 #l (cols 2l,2l+1 of a 140-col tile with
    // 6+6 halo; local col i = global wc0-6+i); lanes 58..63 also h2 #(64+l-58).
    const int  g0  = wc0 - 6 + 2 * lane;
    const bool ok0 = (g0 >= 0) && (g0 < IMG_W);
    const bool on1 = (lane >= 58);
    const int  g1  = wc0 + 6 + 2 * lane;
    const bool ok1 = on1 && (g1 < IMG_W);

    auto ldd = [&](int r, bool ok, int g) -> float2 {   // d = y-x, zero OOB
        float2 v = make_float2(0.f, 0.f);
        if (ok && r >= 0 && r < IMG_H) {
            const float2 a  = *(const float2*)(xi + (size_t)r * IMG_W + g);
            const float2 bb = *(const float2*)(yi + (size_t)r * IMG_W + g);
            v = make_float2(bb.x - a.x, bb.y - a.y);
        }
        return v;
    };
    auto stage = [&](int buf, float2 v0, float2 v1) {
        h2 a; a.x = (_Float16)v0.x; a.y = (_Float16)v0.y;
        sdw[w][buf][lane] = a;
        if (on1) {
            h2 b; b.x = (_Float16)v1.x; b.y = (_Float16)v1.y;
            sdw[w][buf][64 + (lane - 58)] = b;
        }
    };

    // 2-parity packed weights for the column pair (2l, 2l+1):
    // window halfs [2*hb .. 2*hb+15], hb = lane&~1; tap u of col0 at
    // j = u + off (off = 2*(lane&1)), col1 at j = u + off + 1.
    const int off = 2 * (lane & 1);
    h2 wA[8], wB[8];
#pragma unroll
    for (int t = 0; t < 8; ++t) {
        wA[t].x = (_Float16)0.f; wA[t].y = (_Float16)0.f;
        wB[t].x = (_Float16)0.f; wB[t].y = (_Float16)0.f;
    }
#pragma unroll
    for (int offc = 0; offc <= 2; offc += 2) {
        if (off == offc) {
#pragma unroll
            for (int u = 0; u < 13; ++u) {
                const int ja = u + offc;
                if (ja & 1) wA[ja >> 1].y = (_Float16)kt.ke[u];
                else        wA[ja >> 1].x = (_Float16)kt.ke[u];
                const int jb = u + offc + 1;
                if (jb & 1) wB[jb >> 1].y = (_Float16)kt.ke[u];
                else        wB[jb >> 1].x = (_Float16)kt.ke[u];
            }
        }
    }
    const int hb = lane & ~1;   // even h2-index window base

    f2v acc[13];
#pragma unroll
    for (int i = 0; i < 13; ++i) acc[i] = (f2v)0.f;

    // prologue: row rin0 -> buf0; prefetch rin0+1 -> set1, rin0+2 -> set0
    stage(0, ldd(rin0, ok0, g0), ldd(rin0, ok1, g1));
    float2 pf0[2], pf1[2];
    pf0[1] = ldd(rin0 + 1, ok0, g0); pf1[1] = ldd(rin0 + 1, ok1, g1);
    pf0[0] = ldd(rin0 + 2, ok0, g0); pf1[0] = ldd(rin0 + 2, ok1, g1);
    WAVE_FENCE();

#pragma unroll 1
    for (int c2 = 0; c2 < 2; ++c2) {
        const int rbase = c2 * 26;
#pragma unroll
        for (int p26 = 0; p26 < 26; ++p26) {
            const int rr  = rbase + p26;
            const int p13 = p26 % 13;       // static ring phase
            const int b   = p26 & 1;        // static buffer parity
            if (rr <= 43) {
                // h-pass: 4 ds_read_b64 + 16 fdot2 give both columns
                float a0 = 0.f, a1 = 0.f;
#pragma unroll
                for (int k = 0; k < 4; ++k) {
                    const h4 v = *(const h4*)&sdw[w][b][hb + 2 * k];
                    const h2 vl = lo2(v), vh = hi2(v);
                    a0 = FDOT2(wA[2 * k], vl, a0); a0 = FDOT2(wA[2 * k + 1], vh, a0);
                    a1 = FDOT2(wB[2 * k], vl, a1); a1 = FDOT2(wB[2 * k + 1], vh, a1);
                }
                if (rr < 43) stage(b ^ 1, pf0[(p26 + 1) & 1], pf1[(p26 + 1) & 1]);
                if (rr < 41) {
                    pf0[(p26 + 1) & 1] = ldd(rin0 + rr + 3, ok0, g0);
                    pf1[(p26 + 1) & 1] = ldd(rin0 + rr + 3, ok1, g1);
                }
                // v-pass: 13 packed FMAs into mod-13 pending slots
                f2v hv; hv.x = a0; hv.y = a1;
#pragma unroll
                for (int d = 0; d <= 12; ++d) {
                    const int s = (p13 + 13 - d) % 13;
                    f2v wv; wv.x = kt.ke[d]; wv.y = kt.ke[d];
                    acc[s] += wv * hv;
                }
                {
                    const int sc = (p13 + 1) % 13;
                    const int ro = rr - 12;
                    if (ro >= 0) {
                        const int o = o0 + ro;   // always in [0,511]
                        f2v r;
                        r.x = fmaf(16.f, fabsf(acc[sc].x), base);
                        r.y = fmaf(16.f, fabsf(acc[sc].y), base);
                        *(f2v*)&oi[(size_t)o * IMG_W + wc0 + 2 * lane] = r;
                    }
                    acc[sc] = (f2v)0.f;   // ALWAYS reset
                }
                WAVE_FENCE();
            }
        }
    }
}

extern "C" void kernel_launch(void* const* d_in, const int* in_sizes, int n_in,
                              void* d_out, int out_size, void* d_ws, size_t ws_size,
                              hipStream_t stream) {
    const float* x = (const float*)d_in[0];
    const float* y = (const float*)d_in[1];
    float* out = (float*)d_out;
    double* ssum = (double*)d_ws;

    KTaps kt;
    {   // normalized gaussian win=11 sigma=1.5 (exp-based)
        double g[11], s = 0.0;
        for (int i = 0; i < 11; ++i) {
            const double d = (double)i - 5.0;
            g[i] = std::exp(-(d * d) / 4.5);
            s += g[i];
        }
        for (int i = 0; i < 11; ++i) kt.kw[i] = (float)(g[i] / s);
    }
    {   // erf-gaussian, tail=6 -> 13 taps, sigma=1.5, NOT normalized
        const double t = 0.70710678 / 1.5;
        for (int i = 0; i < 13; ++i) {
            const double xx = (double)i - 6.0;
            const double v = 0.5 * (std::erf(t * (xx + 0.5)) - std::erf(t * (xx - 0.5)));
            kt.ke[i] = (float)(v < 0.0 ? 0.0 : v);
        }
    }

    hipMemsetAsync(ssum, 0, sizeof(double), stream);

    ssim_band_kernel<<<dim3(2, 8, NIMG), dim3(256), 0, stream>>>(x, y, ssum, kt);
    l1_band_kernel<<<dim3(16, NIMG, 1), dim3(256), 0, stream>>>(x, y, ssum, out, kt);
}